// Round 4
// baseline (938.187 us; speedup 1.0000x reference)
//
#include <hip/hip_runtime.h>
#include <hip/hip_cooperative_groups.h>
#include <cstddef>

namespace cg = cooperative_groups;

constexpr int kDIn  = 1024;
constexpr int kDOut = 1024;
constexpr int kBatch = 32;
constexpr int kE = kDOut + 2 * kDIn + 4;   // 3076
constexpr int kKQRows = 2 * kDIn + 4;      // 2052 rows, starting at e = kDOut
constexpr int kRowsKQ = kBatch * kKQRows;  // 65664
constexpr int kRowsTotal = kBatch * kE;    // 98432

typedef float floatx4 __attribute__((ext_vector_type(4)));  // native vec for nt builtins

__device__ __forceinline__ float dot4(float4 a, float4 b) {
    return a.x * b.x + a.y * b.y + a.z * b.z + a.w * b.w;
}
__device__ __forceinline__ float dot4v(floatx4 a, float4 b) {
    return a.x * b.x + a.y * b.y + a.z * b.z + a.w * b.w;
}

// ---------------------------------------------------------------------------
// Wave64 sum via DPP (pure VALU, no LDS). After this, lane 63 holds the sum.
// ---------------------------------------------------------------------------
__device__ __forceinline__ float dppSumTo63(float v) {
    int t;
    t = __builtin_amdgcn_update_dpp(0, __float_as_int(v), 0x111, 0xf, 0xf, true); v += __int_as_float(t);
    t = __builtin_amdgcn_update_dpp(0, __float_as_int(v), 0x112, 0xf, 0xf, true); v += __int_as_float(t);
    t = __builtin_amdgcn_update_dpp(0, __float_as_int(v), 0x114, 0xf, 0xf, true); v += __int_as_float(t);
    t = __builtin_amdgcn_update_dpp(0, __float_as_int(v), 0x118, 0xf, 0xf, true); v += __int_as_float(t);
    t = __builtin_amdgcn_update_dpp(0, __float_as_int(v), 0x142, 0xa, 0xf, true); v += __int_as_float(t);
    t = __builtin_amdgcn_update_dpp(0, __float_as_int(v), 0x143, 0xc, 0xf, true); v += __int_as_float(t);
    return v;
}
__device__ __forceinline__ float waveBcast63(float v) {
    return __int_as_float(__builtin_amdgcn_readlane(__float_as_int(v), 63));
}

// ---------------------------------------------------------------------------
// Phase bodies (shared between fused kernel and 3-kernel fallback)
// ---------------------------------------------------------------------------
__device__ __forceinline__ void matvec_kq_row(int gw, int lane,
                                              const float* __restrict__ w,
                                              const float* __restrict__ x,
                                              float* __restrict__ outv) {
    const int b = gw / kKQRows;
    const int e = kDOut + (gw - b * kKQRows);
    const float4* __restrict__ wr = (const float4*)(w + ((size_t)b * kE + e) * kDIn);
    const float4* __restrict__ xr = (const float4*)(x + (size_t)b * kDIn);
    float acc = 0.f;
#pragma unroll
    for (int it = 0; it < 4; ++it) {
        const int idx = it * 64 + lane;
        acc += dot4(wr[idx], xr[idx]);
    }
    acc = dppSumTo63(acc);
    if (lane == 63) outv[(size_t)b * kE + e] = acc;
}

__device__ __forceinline__ void softmax_pair_body(int b, int tid,
                                                  const float* __restrict__ outv,
                                                  float* __restrict__ kphi,
                                                  float* __restrict__ dphi) {
    const float* __restrict__ base = outv + (size_t)b * kE + kDOut;
    const float4 kv = ((const float4*)base)[tid];
    const float4 qv = ((const float4*)(base + kDIn))[tid];

    float mk = fmaxf(fmaxf(kv.x, kv.y), fmaxf(kv.z, kv.w));
    float mq = fmaxf(fmaxf(qv.x, qv.y), fmaxf(qv.z, qv.w));
#pragma unroll
    for (int off = 32; off; off >>= 1) {
        mk = fmaxf(mk, __shfl_xor(mk, off, 64));
        mq = fmaxf(mq, __shfl_xor(mq, off, 64));
    }
    __shared__ float smk[4], smq[4];
    if ((tid & 63) == 0) { smk[tid >> 6] = mk; smq[tid >> 6] = mq; }
    __syncthreads();
    mk = fmaxf(fmaxf(smk[0], smk[1]), fmaxf(smk[2], smk[3]));
    mq = fmaxf(fmaxf(smq[0], smq[1]), fmaxf(smq[2], smq[3]));

    float4 ek, eq;
    ek.x = __expf(kv.x - mk); ek.y = __expf(kv.y - mk);
    ek.z = __expf(kv.z - mk); ek.w = __expf(kv.w - mk);
    eq.x = __expf(qv.x - mq); eq.y = __expf(qv.y - mq);
    eq.z = __expf(qv.z - mq); eq.w = __expf(qv.w - mq);
    float sk = ek.x + ek.y + ek.z + ek.w;
    float sq = eq.x + eq.y + eq.z + eq.w;
#pragma unroll
    for (int off = 32; off; off >>= 1) {
        sk += __shfl_xor(sk, off, 64);
        sq += __shfl_xor(sq, off, 64);
    }
    __shared__ float ssk[4], ssq[4];
    if ((tid & 63) == 0) { ssk[tid >> 6] = sk; ssq[tid >> 6] = sq; }
    __syncthreads();
    sk = ssk[0] + ssk[1] + ssk[2] + ssk[3];
    sq = ssq[0] + ssq[1] + ssq[2] + ssq[3];
    const float ik = 1.f / sk;
    const float iq = 1.f / sq;

    float4 kp, dp;
    kp.x = ek.x * ik; kp.y = ek.y * ik; kp.z = ek.z * ik; kp.w = ek.w * ik;
    dp.x = eq.x * iq - kp.x; dp.y = eq.y * iq - kp.y;
    dp.z = eq.z * iq - kp.z; dp.w = eq.w * iq - kp.w;
    ((float4*)(kphi + (size_t)b * kDIn))[tid] = kp;
    ((float4*)(dphi + (size_t)b * kDIn))[tid] = dp;
}

__device__ __forceinline__ void update_row(int gw, int lane,
                                           const float* __restrict__ w,
                                           const float* __restrict__ x,
                                           const float* __restrict__ outv,
                                           const float* __restrict__ kphi,
                                           const float* __restrict__ dphi,
                                           float* __restrict__ y_out,
                                           float* __restrict__ w_out) {
    int b, e;
    bool isY;
    if (gw < kRowsKQ) {                       // kq rows, reversed (MRU-first)
        const int idx = kRowsKQ - 1 - gw;
        b = idx / kKQRows;
        e = kDOut + (idx - b * kKQRows);
        isY = false;
    } else {                                  // y rows, ascending
        const int gy = gw - kRowsKQ;
        b = gy >> 10;
        e = gy & 1023;
        isY = true;
    }

    const size_t row_off = ((size_t)b * kE + e) * kDIn;
    const float4*  __restrict__ wr  = (const float4*)(w + row_off);
    const floatx4* __restrict__ wrn = (const floatx4*)(w + row_off);
    const float4*  __restrict__ kr  = (const float4*)(kphi + (size_t)b * kDIn);
    const float4*  __restrict__ dr  = (const float4*)(dphi + (size_t)b * kDIn);

    floatx4 wv[4];
    float acc_d = 0.f, acc_y = 0.f;
    if (isY) {
        const float4* __restrict__ xr = (const float4*)(x + (size_t)b * kDIn);
#pragma unroll
        for (int it = 0; it < 4; ++it) {
            const int idx = it * 64 + lane;
            wv[it] = __builtin_nontemporal_load(&wrn[idx]);   // single-use rows
            const float4 dv = dr[idx];
            const float4 xv = xr[idx];
            acc_d += dot4v(wv[it], dv);
            acc_y += dot4v(wv[it], xv);
        }
        acc_d = dppSumTo63(acc_d);
        acc_y = dppSumTo63(acc_y);   // consumed only on lane 63
    } else {
#pragma unroll
        for (int it = 0; it < 4; ++it) {
            const int idx = it * 64 + lane;
            const float4 wl = wr[idx];                        // want L2/L3 hits from phase 1
            wv[it].x = wl.x; wv[it].y = wl.y; wv[it].z = wl.z; wv[it].w = wl.w;
            const float4 dv = dr[idx];
            acc_d += dot4v(wv[it], dv);
        }
        acc_d = dppSumTo63(acc_d);
    }
    acc_d = waveBcast63(acc_d);      // coef needed by all lanes

    const int bi = isY ? 0 : (e < kDOut + kDIn) ? 1 : (e < kDOut + 2 * kDIn) ? 2 : 3;
    const float beta = outv[(size_t)b * kE + (kE - 4) + bi];
    const float sig  = 1.f / (1.f + __expf(-beta));
    const float coef = sig * acc_d;

    floatx4* __restrict__ orow = (floatx4*)(w_out + row_off);
#pragma unroll
    for (int it = 0; it < 4; ++it) {
        const int idx = it * 64 + lane;
        const float4 kv = kr[idx];          // L1-hot reload; keeps VGPRs low
        floatx4 o;
        o.x = wv[it].x + coef * kv.x;
        o.y = wv[it].y + coef * kv.y;
        o.z = wv[it].z + coef * kv.z;
        o.w = wv[it].w + coef * kv.w;
        __builtin_nontemporal_store(o, &orow[idx]);   // no write-allocate
    }

    if (isY && lane == 63) y_out[(size_t)b * kDOut + e] = acc_y;
}

// ---------------------------------------------------------------------------
// Fused persistent cooperative kernel: phase1 matvec -> sync -> softmax ->
// sync -> phase3 update. Removes 2 kernel boundaries (launch gap + full L2
// invalidate each) and keeps phase-1 kq lines L2/L3-hot for phase 3.
// ---------------------------------------------------------------------------
__global__ __launch_bounds__(256) void k_fused(const float* __restrict__ w,
                                               const float* __restrict__ x,
                                               float* __restrict__ outv,
                                               float* __restrict__ kphi,
                                               float* __restrict__ dphi,
                                               float* __restrict__ y_out,
                                               float* __restrict__ w_out) {
    cg::grid_group grid = cg::this_grid();
    const int tid    = threadIdx.x;
    const int lane   = tid & 63;
    const int wib    = tid >> 6;
    const int nWaves = gridDim.x * 4;
    const int wave0  = blockIdx.x * 4 + wib;

    // Phase 1: kq matvec, ascending order
    for (int gw = wave0; gw < kRowsKQ; gw += nWaves)
        matvec_kq_row(gw, lane, w, x, outv);

    grid.sync();

    // Phase 2: softmax pair, 32 blocks
    if (blockIdx.x < kBatch)
        softmax_pair_body(blockIdx.x, tid, outv, kphi, dphi);

    grid.sync();

    // Phase 3: update; kq rows reversed (MRU-first), then y rows
    for (int gw = wave0; gw < kRowsTotal; gw += nWaves)
        update_row(gw, lane, w, x, outv, kphi, dphi, y_out, w_out);
}

// ---------------------------------------------------------------------------
// 3-kernel fallback (identical math; used if cooperative launch unavailable)
// ---------------------------------------------------------------------------
__global__ __launch_bounds__(256) void k_matvec_kq(const float* __restrict__ w,
                                                   const float* __restrict__ x,
                                                   float* __restrict__ outv) {
    const int gw   = (blockIdx.x * 256 + threadIdx.x) >> 6;
    const int lane = threadIdx.x & 63;
    matvec_kq_row(gw, lane, w, x, outv);
}

__global__ __launch_bounds__(256) void k_softmax_pair(const float* __restrict__ outv,
                                                      float* __restrict__ kphi,
                                                      float* __restrict__ dphi) {
    softmax_pair_body(blockIdx.x, threadIdx.x, outv, kphi, dphi);
}

__global__ __launch_bounds__(256) void k_update(const float* __restrict__ w,
                                                const float* __restrict__ x,
                                                const float* __restrict__ outv,
                                                const float* __restrict__ kphi,
                                                const float* __restrict__ dphi,
                                                float* __restrict__ y_out,
                                                float* __restrict__ w_out) {
    const int gw   = (blockIdx.x * 256 + threadIdx.x) >> 6;
    const int lane = threadIdx.x & 63;
    update_row(gw, lane, w, x, outv, kphi, dphi, y_out, w_out);
}

// ---------------------------------------------------------------------------
extern "C" void kernel_launch(void* const* d_in, const int* in_sizes, int n_in,
                              void* d_out, int out_size, void* d_ws, size_t ws_size,
                              hipStream_t stream) {
    const float* x = (const float*)d_in[0];   // (32, 1024)
    const float* w = (const float*)d_in[1];   // (32, 3076, 1024)

    float* y_out = (float*)d_out;                          // 32*1024
    float* w_out = (float*)d_out + (size_t)kBatch * kDOut; // 32*3076*1024

    float* outv = (float*)d_ws;                              // 32*3076
    float* kphi = outv + (size_t)kBatch * kE;                // 32*1024
    float* dphi = kphi + (size_t)kBatch * kDIn;              // 32*1024

    // One-time co-residency sizing for the cooperative launch.
    static int s_gridBlocks = 0;
    if (s_gridBlocks == 0) {
        int perCU = 0, numCU = 0, dev = 0;
        (void)hipGetDevice(&dev);
        hipError_t e1 = hipOccupancyMaxActiveBlocksPerMultiprocessor(&perCU, k_fused, 256, 0);
        hipError_t e2 = hipDeviceGetAttribute(&numCU, hipDeviceAttributeMultiprocessorCount, dev);
        if (e1 != hipSuccess || e2 != hipSuccess || perCU <= 0 || numCU <= 0)
            s_gridBlocks = -1;                 // signal: use fallback
        else
            s_gridBlocks = perCU * numCU;
        if (s_gridBlocks > 0 && s_gridBlocks < kBatch) s_gridBlocks = -1;
    }

    bool coopOK = false;
    if (s_gridBlocks > 0) {
        void* args[] = {(void*)&w, (void*)&x, (void*)&outv, (void*)&kphi,
                        (void*)&dphi, (void*)&y_out, (void*)&w_out};
        hipError_t e = hipLaunchCooperativeKernel(k_fused, dim3(s_gridBlocks), dim3(256),
                                                  args, 0, stream);
        coopOK = (e == hipSuccess);
        if (!coopOK) s_gridBlocks = -1;        // don't retry next launches
    }

    if (!coopOK) {
        k_matvec_kq<<<kRowsKQ / 4, 256, 0, stream>>>(w, x, outv);
        k_softmax_pair<<<kBatch, 256, 0, stream>>>(outv, kphi, dphi);
        k_update<<<kRowsTotal / 4, 256, 0, stream>>>(w, x, outv, kphi, dphi, y_out, w_out);
    }
}

// Round 5
// 765.515 us; speedup vs baseline: 1.2256x; 1.2256x over previous
//
#include <hip/hip_runtime.h>
#include <cstddef>

constexpr int kDIn  = 1024;
constexpr int kDOut = 1024;
constexpr int kBatch = 32;
constexpr int kE = kDOut + 2 * kDIn + 4;   // 3076
constexpr int kKQRows = 2 * kDIn + 4;      // 2052 rows, starting at e = kDOut
constexpr int kRowsKQ = kBatch * kKQRows;  // 65664
constexpr int kRowsTotal = kBatch * kE;    // 98432

typedef float floatx4 __attribute__((ext_vector_type(4)));  // native vec for nt builtins

__device__ __forceinline__ float dot4(float4 a, float4 b) {
    return a.x * b.x + a.y * b.y + a.z * b.z + a.w * b.w;
}
__device__ __forceinline__ float dot4v(floatx4 a, float4 b) {
    return a.x * b.x + a.y * b.y + a.z * b.z + a.w * b.w;
}

// ---------------------------------------------------------------------------
// Wave64 sum via DPP (pure VALU, no LDS). After this, lane 63 holds the sum.
// ---------------------------------------------------------------------------
__device__ __forceinline__ float dppSumTo63(float v) {
    int t;
    t = __builtin_amdgcn_update_dpp(0, __float_as_int(v), 0x111, 0xf, 0xf, true); v += __int_as_float(t);
    t = __builtin_amdgcn_update_dpp(0, __float_as_int(v), 0x112, 0xf, 0xf, true); v += __int_as_float(t);
    t = __builtin_amdgcn_update_dpp(0, __float_as_int(v), 0x114, 0xf, 0xf, true); v += __int_as_float(t);
    t = __builtin_amdgcn_update_dpp(0, __float_as_int(v), 0x118, 0xf, 0xf, true); v += __int_as_float(t);
    t = __builtin_amdgcn_update_dpp(0, __float_as_int(v), 0x142, 0xa, 0xf, true); v += __int_as_float(t);
    t = __builtin_amdgcn_update_dpp(0, __float_as_int(v), 0x143, 0xc, 0xf, true); v += __int_as_float(t);
    return v;
}
__device__ __forceinline__ float waveBcast63(float v) {
    return __int_as_float(__builtin_amdgcn_readlane(__float_as_int(v), 63));
}

// ---------------------------------------------------------------------------
// Kernel 1: out[b][e] = w[b,e,:] . x[b,:]   for e in [kDOut, kE)
// TWO rows per wave: doubles in-flight loads, amortizes reduce bubbles.
// Ascending order (k3 consumes in REVERSE for L3 MRU reuse).
// ---------------------------------------------------------------------------
__global__ __launch_bounds__(256, 8) void k_matvec_kq(const float* __restrict__ w,
                                                      const float* __restrict__ x,
                                                      float* __restrict__ outv) {
    const int gw   = (blockIdx.x * 256 + threadIdx.x) >> 6;  // [0, kRowsKQ/2)
    const int lane = threadIdx.x & 63;
    const int r0 = 2 * gw, r1 = r0 + 1;
    const int b0 = r0 / kKQRows, e0 = kDOut + (r0 - b0 * kKQRows);
    const int b1 = r1 / kKQRows, e1 = kDOut + (r1 - b1 * kKQRows);

    const float4* __restrict__ w0 = (const float4*)(w + ((size_t)b0 * kE + e0) * kDIn);
    const float4* __restrict__ w1 = (const float4*)(w + ((size_t)b1 * kE + e1) * kDIn);
    const float4* __restrict__ x0 = (const float4*)(x + (size_t)b0 * kDIn);
    const float4* __restrict__ x1 = (const float4*)(x + (size_t)b1 * kDIn);

    float a0 = 0.f, a1 = 0.f;
#pragma unroll
    for (int it = 0; it < 4; ++it) {
        const int idx = it * 64 + lane;
        a0 += dot4(w0[idx], x0[idx]);
        a1 += dot4(w1[idx], x1[idx]);
    }
    a0 = dppSumTo63(a0);           // independent chains; compiler interleaves
    a1 = dppSumTo63(a1);
    if (lane == 63) {
        outv[(size_t)b0 * kE + e0] = a0;
        outv[(size_t)b1 * kE + e1] = a1;
    }
}

// ---------------------------------------------------------------------------
// Kernel 2: one block per batch. kphi = softmax(k), dphi = softmax(q)-softmax(k).
// ---------------------------------------------------------------------------
__global__ __launch_bounds__(256) void k_softmax_pair(const float* __restrict__ outv,
                                                      float* __restrict__ kphi,
                                                      float* __restrict__ dphi) {
    const int b   = blockIdx.x;
    const int tid = threadIdx.x;
    const float* __restrict__ base = outv + (size_t)b * kE + kDOut;

    const float4 kv = ((const float4*)base)[tid];
    const float4 qv = ((const float4*)(base + kDIn))[tid];

    float mk = fmaxf(fmaxf(kv.x, kv.y), fmaxf(kv.z, kv.w));
    float mq = fmaxf(fmaxf(qv.x, qv.y), fmaxf(qv.z, qv.w));
#pragma unroll
    for (int off = 32; off; off >>= 1) {
        mk = fmaxf(mk, __shfl_xor(mk, off, 64));
        mq = fmaxf(mq, __shfl_xor(mq, off, 64));
    }
    __shared__ float smk[4], smq[4];
    if ((tid & 63) == 0) { smk[tid >> 6] = mk; smq[tid >> 6] = mq; }
    __syncthreads();
    mk = fmaxf(fmaxf(smk[0], smk[1]), fmaxf(smk[2], smk[3]));
    mq = fmaxf(fmaxf(smq[0], smq[1]), fmaxf(smq[2], smq[3]));

    float4 ek, eq;
    ek.x = __expf(kv.x - mk); ek.y = __expf(kv.y - mk);
    ek.z = __expf(kv.z - mk); ek.w = __expf(kv.w - mk);
    eq.x = __expf(qv.x - mq); eq.y = __expf(qv.y - mq);
    eq.z = __expf(qv.z - mq); eq.w = __expf(qv.w - mq);
    float sk = ek.x + ek.y + ek.z + ek.w;
    float sq = eq.x + eq.y + eq.z + eq.w;
#pragma unroll
    for (int off = 32; off; off >>= 1) {
        sk += __shfl_xor(sk, off, 64);
        sq += __shfl_xor(sq, off, 64);
    }
    __shared__ float ssk[4], ssq[4];
    if ((tid & 63) == 0) { ssk[tid >> 6] = sk; ssq[tid >> 6] = sq; }
    __syncthreads();
    sk = ssk[0] + ssk[1] + ssk[2] + ssk[3];
    sq = ssq[0] + ssq[1] + ssq[2] + ssq[3];
    const float ik = 1.f / sk;
    const float iq = 1.f / sq;

    float4 kp, dp;
    kp.x = ek.x * ik; kp.y = ek.y * ik; kp.z = ek.z * ik; kp.w = ek.w * ik;
    dp.x = eq.x * iq - kp.x; dp.y = eq.y * iq - kp.y;
    dp.z = eq.z * iq - kp.z; dp.w = eq.w * iq - kp.w;
    ((float4*)(kphi + (size_t)b * kDIn))[tid] = kp;
    ((float4*)(dphi + (size_t)b * kDIn))[tid] = dp;
}

// ---------------------------------------------------------------------------
// Kernel 3: TWO rows per wave. Row order: kq rows reversed (MRU-first vs k1,
// plain loads -> L3 hits), then y rows (nt loads, single-use). All w_out
// stores nontemporal. Two/four independent DPP chains per wave.
// ---------------------------------------------------------------------------
__device__ __forceinline__ void mapRow(int r, int& b, int& e) {
    if (r < kRowsKQ) {                        // reversed kq region
        const int idx = kRowsKQ - 1 - r;
        b = idx / kKQRows;
        e = kDOut + (idx - b * kKQRows);
    } else {                                  // y region, ascending
        const int gy = r - kRowsKQ;
        b = gy >> 10;
        e = gy & 1023;
    }
}

__global__ __launch_bounds__(256, 8) void k_update(const float* __restrict__ w,
                                                   const float* __restrict__ x,
                                                   const float* __restrict__ outv,
                                                   const float* __restrict__ kphi,
                                                   const float* __restrict__ dphi,
                                                   float* __restrict__ y_out,
                                                   float* __restrict__ w_out) {
    const int gw   = (blockIdx.x * 256 + threadIdx.x) >> 6;  // [0, kRowsTotal/2)
    const int lane = threadIdx.x & 63;
    const int r0 = 2 * gw, r1 = r0 + 1;

    int b0, e0, b1, e1;
    mapRow(r0, b0, e0);
    mapRow(r1, b1, e1);
    const bool y0 = (r0 >= kRowsKQ);
    const bool y1 = (r1 >= kRowsKQ);

    const size_t off0 = ((size_t)b0 * kE + e0) * kDIn;
    const size_t off1 = ((size_t)b1 * kE + e1) * kDIn;
    const floatx4* __restrict__ w0 = (const floatx4*)(w + off0);
    const floatx4* __restrict__ w1 = (const floatx4*)(w + off1);
    const float4*  __restrict__ dr0 = (const float4*)(dphi + (size_t)b0 * kDIn);
    const float4*  __restrict__ dr1 = (const float4*)(dphi + (size_t)b1 * kDIn);

    floatx4 wv0[4], wv1[4];
    float d0 = 0.f, d1 = 0.f, yy0 = 0.f, yy1 = 0.f;

    if (y0) {
        // both rows are y rows: nt loads (single-use), also need w.x dots
        const float4* __restrict__ x0 = (const float4*)(x + (size_t)b0 * kDIn);
        const float4* __restrict__ x1 = (const float4*)(x + (size_t)b1 * kDIn);
#pragma unroll
        for (int it = 0; it < 4; ++it) {
            const int idx = it * 64 + lane;
            wv0[it] = __builtin_nontemporal_load(&w0[idx]);
            wv1[it] = __builtin_nontemporal_load(&w1[idx]);
            const float4 dv0 = dr0[idx], dv1 = dr1[idx];
            const float4 xv0 = x0[idx],  xv1 = x1[idx];
            d0  += dot4v(wv0[it], dv0);
            d1  += dot4v(wv1[it], dv1);
            yy0 += dot4v(wv0[it], xv0);
            yy1 += dot4v(wv1[it], xv1);
        }
        d0  = dppSumTo63(d0);
        d1  = dppSumTo63(d1);
        yy0 = dppSumTo63(yy0);
        yy1 = dppSumTo63(yy1);
    } else {
        // kq rows (plain loads -> want L3 hits from k1)
#pragma unroll
        for (int it = 0; it < 4; ++it) {
            const int idx = it * 64 + lane;
            wv0[it] = w0[idx];
            wv1[it] = w1[idx];
            d0 += dot4v(wv0[it], dr0[idx]);
            d1 += dot4v(wv1[it], dr1[idx]);
        }
        d0 = dppSumTo63(d0);
        d1 = dppSumTo63(d1);
        if (y1) {  // straddle wave (exactly one in the grid): r1 is a y row
            const float4* __restrict__ x1 = (const float4*)(x + (size_t)b1 * kDIn);
#pragma unroll
            for (int it = 0; it < 4; ++it) {
                const int idx = it * 64 + lane;
                yy1 += dot4v(wv1[it], x1[idx]);
            }
            yy1 = dppSumTo63(yy1);
        }
    }
    d0 = waveBcast63(d0);
    d1 = waveBcast63(d1);

    // beta index: y->b1(0), k->b2(1), q->b3(2), tail 4 rows->b4(3)
    const int bi0 = y0 ? 0 : (e0 < kDOut + kDIn) ? 1 : (e0 < kDOut + 2 * kDIn) ? 2 : 3;
    const int bi1 = y1 ? 0 : (e1 < kDOut + kDIn) ? 1 : (e1 < kDOut + 2 * kDIn) ? 2 : 3;
    const float beta0 = outv[(size_t)b0 * kE + (kE - 4) + bi0];
    const float beta1 = outv[(size_t)b1 * kE + (kE - 4) + bi1];
    const float c0 = d0 / (1.f + __expf(-beta0));   // sigmoid(beta)*d
    const float c1 = d1 / (1.f + __expf(-beta1));

    const float4* __restrict__ kr0 = (const float4*)(kphi + (size_t)b0 * kDIn);
    const float4* __restrict__ kr1 = (const float4*)(kphi + (size_t)b1 * kDIn);
    floatx4* __restrict__ o0 = (floatx4*)(w_out + off0);
    floatx4* __restrict__ o1 = (floatx4*)(w_out + off1);
#pragma unroll
    for (int it = 0; it < 4; ++it) {
        const int idx = it * 64 + lane;
        const float4 kv0 = kr0[idx], kv1 = kr1[idx];   // L1-hot reloads
        floatx4 t0, t1;
        t0.x = wv0[it].x + c0 * kv0.x;  t0.y = wv0[it].y + c0 * kv0.y;
        t0.z = wv0[it].z + c0 * kv0.z;  t0.w = wv0[it].w + c0 * kv0.w;
        t1.x = wv1[it].x + c1 * kv1.x;  t1.y = wv1[it].y + c1 * kv1.y;
        t1.z = wv1[it].z + c1 * kv1.z;  t1.w = wv1[it].w + c1 * kv1.w;
        __builtin_nontemporal_store(t0, &o0[idx]);
        __builtin_nontemporal_store(t1, &o1[idx]);
    }

    if (lane == 63) {
        if (y0) y_out[(size_t)b0 * kDOut + e0] = yy0;
        if (y1) y_out[(size_t)b1 * kDOut + e1] = yy1;
    }
}

// ---------------------------------------------------------------------------
extern "C" void kernel_launch(void* const* d_in, const int* in_sizes, int n_in,
                              void* d_out, int out_size, void* d_ws, size_t ws_size,
                              hipStream_t stream) {
    const float* x = (const float*)d_in[0];   // (32, 1024)
    const float* w = (const float*)d_in[1];   // (32, 3076, 1024)

    float* y_out = (float*)d_out;                          // 32*1024
    float* w_out = (float*)d_out + (size_t)kBatch * kDOut; // 32*3076*1024

    float* outv = (float*)d_ws;                              // 32*3076
    float* kphi = outv + (size_t)kBatch * kE;                // 32*1024
    float* dphi = kphi + (size_t)kBatch * kDIn;              // 32*1024

    // Kernel 1: 65664 rows, 2 rows/wave, 4 waves/block -> 8208 blocks
    k_matvec_kq<<<kRowsKQ / 8, 256, 0, stream>>>(w, x, outv);

    // Kernel 2: one block per batch
    k_softmax_pair<<<kBatch, 256, 0, stream>>>(outv, kphi, dphi);

    // Kernel 3: 98432 rows, 2 rows/wave, 4 waves/block -> 12304 blocks
    k_update<<<kRowsTotal / 8, 256, 0, stream>>>(w, x, outv, kphi, dphi, y_out, w_out);
}